// Round 16
// baseline (248.854 us; speedup 1.0000x reference)
//
#include <hip/hip_runtime.h>
#include <hip/hip_fp16.h>

// DGCF single-layer, 2 routing iters (MI355X). fp32 in / fp32 out.
// R30 = R29/R25 with Ttab DELETED: zat phase B recomputes tanh from the
// Xh rows phase A just fetched (per-block working set ~14KB, L2-hot).
// Rationale: zat 64us @ FETCH 151MB = gathers of TWO 7.68MB tables
// (15.4MB footprint vs 4MB/XCD L2 -> 26% hit). Ttab[t] is a pure
// function of Xh[t] and a per-(node,intent) scalar invx:
//   - invx4[n][4] (960KB, L2-resident broadcast) replaces Ttab (7.68MB).
//   - phase B: re-gather Xh row (same lines phase A touched -> mostly
//     L2-hit), t = (e^{2y}-1)/(e^{2y}+1), y = x*invx; |y|<=1 since
//     |x_c| <= ||x||_intent -> no overflow. fp32 dot (removes Ttab's
//     half rounding; adds half-x input error of same magnitude).
//   - Xh footprint alone: 7.68MB -> ~50% hit for remaining misses.
// Everything else byte-identical to R29 (best measured 234.9/236.5us):
// count||prep overlap, scan+d0a, atomic-free rank scatter, zat LDS
// fusion, outk single-visit full-line gathers over warm Xh.

#define NUSERS 30000
#define NN     60000
#define EE     800000
#define SCAN_B ((NN + 255) / 256)       // 235 scan blocks
#define EV_B   ((EE / 4 + 255) / 256)   // 782 int4 edge blocks
#define NW1_B  ((NN + 1 + 3) / 4)       // 15001 prep node blocks (incl zero row)
#define N8_B   (NN / 8)                 // 7500 blocks (8 nodes; 8 | NN)

__device__ __forceinline__ float getX(const float* __restrict__ Gu,
                                      const float* __restrict__ Gi,
                                      int n, int c) {
    return (n < NUSERS) ? Gu[n * 64 + c] : Gi[(n - NUSERS) * 64 + c];
}

__device__ __forceinline__ int clampN(int n) {
    return ((unsigned)n < (unsigned)NN) ? n : 0;
}

// |y| <= 1 guaranteed by construction (|x_c| <= intent norm) -> e in
// [e^-2, e^2], no overflow, no NaN.
__device__ __forceinline__ float fast_tanh(float y) {
    float e = __expf(2.f * y);
    return (e - 1.f) * __frcp_rn(e + 1.f);
}

// dot contribution of one half2 pair: z.z*tanh(x.x*iv) + z.y*tanh(x.y*iv)
__device__ __forceinline__ float pair_dot(float zbits, float xbits, float iv) {
    float2 z = __half22float2(__builtin_bit_cast(__half2, zbits));
    float2 x = __half22float2(__builtin_bit_cast(__half2, xbits));
    return z.x * fast_tanh(x.x * iv) + z.y * fast_tanh(x.y * iv);
}

// ---- merged dispatch: edge_count (blocks [0,EV_B)) || prep (rest) ----
// count: degrees + per-edge rank (atomicAdd return), rank stored int4.
// prep: Xh[n][64] = half(X row), invx4[n][4] = per-intent 1/||x||.
__global__ void count_prep(const int* __restrict__ eh, int* __restrict__ deg0,
                           int* __restrict__ rank,
                           const float* __restrict__ Gu, const float* __restrict__ Gi,
                           __half* __restrict__ Xh, float* __restrict__ invx4) {
    if (blockIdx.x < EV_B) {
        int e4 = (blockIdx.x * 256 + threadIdx.x) * 4;
        if (e4 >= EE) return;
        int4 h = *(const int4*)(eh + e4);
        int4 r;
        r.x = atomicAdd(&deg0[clampN(h.x)], 1);
        r.y = atomicAdd(&deg0[clampN(h.y)], 1);
        r.z = atomicAdd(&deg0[clampN(h.z)], 1);
        r.w = atomicAdd(&deg0[clampN(h.w)], 1);
        *(int4*)(rank + e4) = r;
    } else {
        int n = (blockIdx.x - EV_B) * 4 + (threadIdx.x >> 6);
        if (n > NN) return;                     // zero row at n == NN
        int lane = threadIdx.x & 63;            // lane == channel c
        float x = (n < NN) ? getX(Gu, Gi, n, lane) : 0.f;
        float sx = x * x;
        #pragma unroll
        for (int m = 1; m < 16; m <<= 1) sx += __shfl_xor(sx, m, 64);  // 16-ch intent group
        float invx = rsqrtf(fmaxf(sx, 1e-12f));
        Xh[(size_t)n * 64 + lane] = __float2half(x);
        if ((lane & 15) == 0) invx4[(size_t)n * 4 + (lane >> 4)] = invx;
    }
}

// In-block exclusive scan of 256 ints; also writes d0a (free: deg0 loaded).
__global__ void scan_local(const int* __restrict__ deg0, int* __restrict__ offsets,
                           int* __restrict__ bsum, float* __restrict__ d0a) {
    int gid = blockIdx.x * 256 + threadIdx.x;
    int lane = threadIdx.x & 63, w = threadIdx.x >> 6;
    int vdeg = (gid < NN) ? deg0[gid] : 0;
    if (gid < NN) d0a[gid] = rsqrtf(fmaxf(0.25f * (float)vdeg, 1e-30f));
    if (gid == NN) d0a[NN] = 0.f;               // zero row
    int x = vdeg;
    #pragma unroll
    for (int d = 1; d < 64; d <<= 1) {
        int y = __shfl_up(x, d, 64);
        if (lane >= d) x += y;
    }
    __shared__ int wsum[4];
    if (lane == 63) wsum[w] = x;
    __syncthreads();
    int wpre = 0;
    #pragma unroll
    for (int j = 0; j < 4; ++j) wpre += (j < w) ? wsum[j] : 0;
    int incl = x + wpre;
    if (gid < NN) offsets[gid] = incl - vdeg;
    if (threadIdx.x == 255) bsum[blockIdx.x] = incl;
}

// Each block re-scans the 235 block sums (cheap) and adds its own prefix.
__global__ void scan_add2(int* __restrict__ offsets, const int* __restrict__ bsum) {
    int tid = threadIdx.x, lane = tid & 63, w = tid >> 6;
    int vv = (tid < SCAN_B) ? bsum[tid] : 0;
    int x = vv;
    #pragma unroll
    for (int d = 1; d < 64; d <<= 1) {
        int y = __shfl_up(x, d, 64);
        if (lane >= d) x += y;
    }
    __shared__ int wsum[4];
    __shared__ int bpre;
    if (lane == 63) wsum[w] = x;
    __syncthreads();
    int wpre = 0;
    #pragma unroll
    for (int j = 0; j < 4; ++j) wpre += (j < w) ? wsum[j] : 0;
    if (tid == blockIdx.x) bpre = x + wpre - vv;   // exclusive prefix of this block
    __syncthreads();
    int gid = blockIdx.x * 256 + tid;
    if (gid < NN) offsets[gid] += bpre;
    if (gid == 0) offsets[NN] = EE;
}

// ---- scatter: atomic-free permute; ONE scattered 4B (tail) store/edge ----
__global__ void scatter(const int* __restrict__ eh, const int* __restrict__ et,
                        const int* __restrict__ rank, const int* __restrict__ offsets,
                        int* __restrict__ csr_tail) {
    int e4 = (blockIdx.x * 256 + threadIdx.x) * 4;
    if (e4 >= EE) return;
    int4 h = *(const int4*)(eh + e4);
    int4 t = *(const int4*)(et + e4);
    int4 r = *(const int4*)(rank + e4);
    int s0 = offsets[clampN(h.x)] + r.x;
    if ((unsigned)s0 < EE) csr_tail[s0] = clampN(t.x);
    int s1 = offsets[clampN(h.y)] + r.y;
    if ((unsigned)s1 < EE) csr_tail[s1] = clampN(t.y);
    int s2 = offsets[clampN(h.z)] + r.z;
    if ((unsigned)s2 < EE) csr_tail[s2] = clampN(t.z);
    int s3 = offsets[clampN(h.w)] + r.w;
    if ((unsigned)s3 < EE) csr_tail[s3] = clampN(t.w);
}

// ---- zat: fused Z-accum + per-edge dots/softmax + deg sums (8 nodes) ----
__global__ void zat(const int* __restrict__ offsets, const int* __restrict__ csr_tail,
                    const __half* __restrict__ Xh, const float* __restrict__ d0a,
                    const float* __restrict__ invx4,
                    __half* __restrict__ s4, float* __restrict__ dcol1) {
    __shared__ __half zn[8][72];        // 144B row stride (16B-aligned rows)
    __shared__ float ssum[8][4];        // per-node per-intent score sums
    __shared__ int soff[9];
    int tid = threadIdx.x;
    int n0 = blockIdx.x * 8;            // 8 | NN, always full
    if (tid < 9) soff[tid] = offsets[n0 + tid];
    if (tid >= 32 && tid < 64) ssum[(tid - 32) >> 2][tid & 3] = 0.f;
    __syncthreads();

    // phase A: per 32-lane group, accumulate Z = sum d0[t]*Xh[t], norm -> LDS
    {
        int g = tid >> 5, cc = tid & 31;
        int s0 = soff[g], s1 = soff[g + 1];
        float accx = 0.f, accy = 0.f;
        for (int base = s0; base < s1; base += 4) {
            #pragma unroll
            for (int u = 0; u < 4; ++u) {
                int kk = base + u;
                bool act = kk < s1;
                int kc = act ? kk : s0;          // in-bounds; deg >= 1 always
                int t = act ? csr_tail[kc] : NN; // NN = zero row (Xh row = 0)
                float d0v = d0a[t];              // broadcast, L2-resident
                __half2 y = *(const __half2*)(Xh + (size_t)t * 64 + cc * 2);
                float2 yf = __half22float2(y);
                accx = fmaf(d0v, yf.x, accx);
                accy = fmaf(d0v, yf.y, accy);
            }
        }
        float ss = accx * accx + accy * accy;
        ss += __shfl_xor(ss, 1, 64);
        ss += __shfl_xor(ss, 2, 64);
        ss += __shfl_xor(ss, 4, 64);             // 8-lane group = 1 intent
        float inv = rsqrtf(fmaxf(ss, 1e-12f));
        *(__half2*)&zn[g][cc * 2] = __floats2half2_rn(accx * inv, accy * inv);
    }
    __syncthreads();

    // phase B: per-edge dots + softmax. tanh recomputed from the Xh rows
    // phase A just fetched (L2-hot); Ttab deleted.
    int e0 = soff[0], e1 = soff[8];
    for (int k = e0 + tid; k < e1; k += 256) {
        int hl = 0;
        #pragma unroll
        for (int j = 1; j < 8; ++j) hl += (k >= soff[j]) ? 1 : 0;
        int t = csr_tail[k];
        float4 iv = *(const float4*)(invx4 + (size_t)t * 4);
        const float4* xp = (const float4*)(Xh + (size_t)t * 64);
        float dot[4];
        #pragma unroll
        for (int i = 0; i < 4; ++i) {
            float ivi = (i == 0) ? iv.x : (i == 1) ? iv.y : (i == 2) ? iv.z : iv.w;
            float4 xa = xp[2 * i], xb = xp[2 * i + 1];
            float4 za = *(const float4*)&zn[hl][i * 16];
            float4 zb = *(const float4*)&zn[hl][i * 16 + 8];
            float d = 0.f;
            d += pair_dot(za.x, xa.x, ivi);
            d += pair_dot(za.y, xa.y, ivi);
            d += pair_dot(za.z, xa.z, ivi);
            d += pair_dot(za.w, xa.w, ivi);
            d += pair_dot(zb.x, xb.x, ivi);
            d += pair_dot(zb.y, xb.y, ivi);
            d += pair_dot(zb.z, xb.z, ivi);
            d += pair_dot(zb.w, xb.w, ivi);
            dot[i] = d;
        }
        float mx = fmaxf(fmaxf(dot[0], dot[1]), fmaxf(dot[2], dot[3]));
        float q0 = __expf(dot[0] - mx), q1 = __expf(dot[1] - mx);
        float q2 = __expf(dot[2] - mx), q3 = __expf(dot[3] - mx);
        float inv = 1.f / (q0 + q1 + q2 + q3);
        q0 *= inv; q1 *= inv; q2 *= inv; q3 *= inv;
        __half2 o01 = __floats2half2_rn(q0, q1);
        __half2 o23 = __floats2half2_rn(q2, q3);
        int2 st;
        st.x = __builtin_bit_cast(int, o01);
        st.y = __builtin_bit_cast(int, o23);
        *(int2*)(s4 + (size_t)k * 4) = st;
        atomicAdd(&ssum[hl][0], q0);
        atomicAdd(&ssum[hl][1], q1);
        atomicAdd(&ssum[hl][2], q2);
        atomicAdd(&ssum[hl][3], q3);
    }
    __syncthreads();

    // phase C: dcol1 from LDS sums
    if (tid < 32) {
        int nn = n0 + (tid >> 2);
        dcol1[nn * 4 + (tid & 3)] = rsqrtf(fmaxf(ssum[tid >> 2][tid & 3], 1e-30f));
    }
}

// ---- output pass: Z2 gather + finalize (R25 verified form) ----
__global__ void outk(const int* __restrict__ offsets, const int* __restrict__ csr_tail,
                     const __half* __restrict__ Xh, const __half* __restrict__ s4,
                     const float* __restrict__ dcol1,
                     const float* __restrict__ Gu, const float* __restrict__ Gi,
                     float* __restrict__ out) {
    int tid = threadIdx.x;
    int n = blockIdx.x * 8 + (tid >> 5);
    if (n >= NN) return;
    int cc = tid & 31;                           // half2-channel (2cc, 2cc+1)
    int i = cc >> 3;                             // intent of this lane's channels
    int s0 = offsets[n], s1 = offsets[n + 1];
    float accx = 0.f, accy = 0.f;
    for (int base = s0; base < s1; base += 4) {
        #pragma unroll
        for (int u = 0; u < 4; ++u) {
            int kk = base + u;
            bool act = kk < s1;
            int kc = act ? kk : s0;              // in-bounds; deg >= 1 always
            int t = csr_tail[kc];
            int2 raw = *(const int2*)(s4 + (size_t)kc * 4);
            int word = (cc & 16) ? raw.y : raw.x;
            unsigned short us = (unsigned short)(word >> ((cc & 8) ? 16 : 0));
            float s = act ? __half2float(__builtin_bit_cast(__half, us)) : 0.f;
            float w = s * dcol1[t * 4 + i];      // s * d1[tail][intent]
            __half2 y = *(const __half2*)(Xh + (size_t)t * 64 + cc * 2);
            float2 yf = __half22float2(y);
            accx = fmaf(w, yf.x, accx);
            accy = fmaf(w, yf.y, accy);
        }
    }
    float d = dcol1[n * 4 + i];
    int ch = cc * 2;
    const float* xr = (n < NUSERS) ? (Gu + (size_t)n * 64 + ch)
                                   : (Gi + (size_t)(n - NUSERS) * 64 + ch);
    float2 x2 = *(const float2*)xr;
    float2 o;
    o.x = 0.5f * (x2.x + d * accx);
    o.y = 0.5f * (x2.y + d * accy);
    *(float2*)(out + (size_t)n * 64 + ch) = o;
}

// ---- launch ----

extern "C" void kernel_launch(void* const* d_in, const int* in_sizes, int n_in,
                              void* d_out, int out_size, void* d_ws, size_t ws_size,
                              hipStream_t stream) {
    const float* Gu = (const float*)d_in[0];
    const float* Gi = (const float*)d_in[1];
    const int* eh = (const int*)d_in[2];
    const int* et = (const int*)d_in[3];
    float* out = (float*)d_out;

    char* p = (char*)d_ws;
    __half* s4       = (__half*)p;     p += (size_t)EE * 4 * 2;       // 6.4 MB
    int*    csr_tail = (int*)p;        p += (size_t)EE * 4;           // 3.2 MB
    int*    rank     = (int*)p;        p += (size_t)EE * 4;           // 3.2 MB
    int*    offsets  = (int*)p;        p += ((size_t)(NN + 1) * 4 + 15) / 16 * 16;
    int*    deg0     = (int*)p;        p += (size_t)NN * 4;
    int*    bsum     = (int*)p;        p += ((size_t)SCAN_B * 4 + 15) / 16 * 16;
    float*  dcol1    = (float*)p;      p += (size_t)NN * 4 * 4;       // 960 KB
    float*  d0a      = (float*)p;      p += ((size_t)(NN + 1) * 4 + 15) / 16 * 16;
    float*  invx4    = (float*)p;      p += (size_t)(NN + 1) * 4 * 4; // 960 KB
    __half* Xh       = (__half*)p;     // (NN+1)*64*2 = 7.68 MB -> total ~23 MB

    // CSR build: count (+rank) overlapped with table prep
    hipMemsetAsync(deg0, 0, NN * sizeof(int), stream);
    count_prep<<<EV_B + NW1_B, 256, 0, stream>>>(eh, deg0, rank, Gu, Gi, Xh, invx4);
    scan_local<<<SCAN_B, 256, 0, stream>>>(deg0, offsets, bsum, d0a);
    scan_add2<<<SCAN_B, 256, 0, stream>>>(offsets, bsum);

    // atomic-free edge permute (tail-only 4B scatter)
    scatter<<<EV_B, 256, 0, stream>>>(eh, et, rank, offsets, csr_tail);

    // fused iter-0: Z-accum + dots (tanh recomputed, Ttab deleted) + softmax
    zat<<<N8_B, 256, 0, stream>>>(offsets, csr_tail, Xh, d0a, invx4, s4, dcol1);

    // iter 1 propagate + finalize: d1 in-register, shared warm Xh table
    outk<<<N8_B, 256, 0, stream>>>(offsets, csr_tail, Xh, s4, dcol1, Gu, Gi, out);
}

// Round 18
// 234.771 us; speedup vs baseline: 1.0600x; 1.0600x over previous
//
#include <hip/hip_runtime.h>
#include <hip/hip_fp16.h>

// DGCF single-layer, 2 routing iters (MI355X). fp32 in / fp32 out.
// R32 = R31 resubmitted verbatim (previous bench died with "container
// failed twice" before executing anything — infra error, same as R1/R16).
// This structure is the twice-verified best: 234.9us (R11), 236.5us (R15).
// Exploration ledger (all measured, closing the space):
//  - R30 (tanh recompute, Ttab deleted): 248.9 — 51M transcendentals
//    (VALUBusy 48%) >> saved fill traffic; aggregate random gathers from
//    ~100 co-resident blocks thrash the 4MB XCD L2, so phase-B "re-reads"
//    miss anyway (FETCH only 151->134MB).
//  - R26/R27/R28 (intent slicing family): 258/246/250 — outk 4-visit
//    regression / lookup latency / VALU compare cost.
//  - R22 (coop mega-kernel): grid.sync flushes non-coherent XCD L2s.
//  - R23/R20: neutral.
// zat's 64us = 151MB random 128B-row gather fill at ~2.4TB/s, a rate
// reproduced across 4 structural variants = measured ceiling for this
// access pattern; byte-reduction levers (fp8, slicing, recompute) are
// measured or absmax-bound dead ends. This is the roofline kernel.

#define NUSERS 30000
#define NN     60000
#define EE     800000
#define SCAN_B ((NN + 255) / 256)       // 235 scan blocks
#define EV_B   ((EE / 4 + 255) / 256)   // 782 int4 edge blocks
#define NW1_B  ((NN + 1 + 3) / 4)       // 15001 prep node blocks (incl zero row)
#define N8_B   (NN / 8)                 // 7500 blocks (8 nodes; 8 | NN)

__device__ __forceinline__ float getX(const float* __restrict__ Gu,
                                      const float* __restrict__ Gi,
                                      int n, int c) {
    return (n < NUSERS) ? Gu[n * 64 + c] : Gi[(n - NUSERS) * 64 + c];
}

__device__ __forceinline__ int clampN(int n) {
    return ((unsigned)n < (unsigned)NN) ? n : 0;
}

__device__ __forceinline__ __half2 bch2(float f) {
    return __builtin_bit_cast(__half2, f);
}

// ---- merged dispatch: edge_count (blocks [0,EV_B)) || prep (rest) ----
// count: degrees + per-edge rank (atomicAdd return), rank stored int4.
// prep: Xh[n][64] = half(X row), Ttab[n][64] = tanh(l2norm-per-intent X).
// prep does NOT read deg0 -> no hazard with counting atomics.
__global__ void count_prep(const int* __restrict__ eh, int* __restrict__ deg0,
                           int* __restrict__ rank,
                           const float* __restrict__ Gu, const float* __restrict__ Gi,
                           __half* __restrict__ Xh, __half* __restrict__ Ttab) {
    if (blockIdx.x < EV_B) {
        int e4 = (blockIdx.x * 256 + threadIdx.x) * 4;
        if (e4 >= EE) return;
        int4 h = *(const int4*)(eh + e4);
        int4 r;
        r.x = atomicAdd(&deg0[clampN(h.x)], 1);
        r.y = atomicAdd(&deg0[clampN(h.y)], 1);
        r.z = atomicAdd(&deg0[clampN(h.z)], 1);
        r.w = atomicAdd(&deg0[clampN(h.w)], 1);
        *(int4*)(rank + e4) = r;
    } else {
        int n = (blockIdx.x - EV_B) * 4 + (threadIdx.x >> 6);
        if (n > NN) return;                     // zero row at n == NN
        int lane = threadIdx.x & 63;            // lane == channel c
        float x = (n < NN) ? getX(Gu, Gi, n, lane) : 0.f;
        float sx = x * x;
        #pragma unroll
        for (int m = 1; m < 16; m <<= 1) sx += __shfl_xor(sx, m, 64);  // 16-ch intent group
        float invx = rsqrtf(fmaxf(sx, 1e-12f));
        size_t a = (size_t)n * 64 + lane;
        Xh[a]   = __float2half(x);
        Ttab[a] = __float2half(tanhf(x * invx));
    }
}

// In-block exclusive scan of 256 ints; also writes d0a (free: deg0 loaded).
__global__ void scan_local(const int* __restrict__ deg0, int* __restrict__ offsets,
                           int* __restrict__ bsum, float* __restrict__ d0a) {
    int gid = blockIdx.x * 256 + threadIdx.x;
    int lane = threadIdx.x & 63, w = threadIdx.x >> 6;
    int vdeg = (gid < NN) ? deg0[gid] : 0;
    if (gid < NN) d0a[gid] = rsqrtf(fmaxf(0.25f * (float)vdeg, 1e-30f));
    if (gid == NN) d0a[NN] = 0.f;               // zero row
    int x = vdeg;
    #pragma unroll
    for (int d = 1; d < 64; d <<= 1) {
        int y = __shfl_up(x, d, 64);
        if (lane >= d) x += y;
    }
    __shared__ int wsum[4];
    if (lane == 63) wsum[w] = x;
    __syncthreads();
    int wpre = 0;
    #pragma unroll
    for (int j = 0; j < 4; ++j) wpre += (j < w) ? wsum[j] : 0;
    int incl = x + wpre;
    if (gid < NN) offsets[gid] = incl - vdeg;
    if (threadIdx.x == 255) bsum[blockIdx.x] = incl;
}

// Each block re-scans the 235 block sums (cheap) and adds its own prefix.
__global__ void scan_add2(int* __restrict__ offsets, const int* __restrict__ bsum) {
    int tid = threadIdx.x, lane = tid & 63, w = tid >> 6;
    int vv = (tid < SCAN_B) ? bsum[tid] : 0;
    int x = vv;
    #pragma unroll
    for (int d = 1; d < 64; d <<= 1) {
        int y = __shfl_up(x, d, 64);
        if (lane >= d) x += y;
    }
    __shared__ int wsum[4];
    __shared__ int bpre;
    if (lane == 63) wsum[w] = x;
    __syncthreads();
    int wpre = 0;
    #pragma unroll
    for (int j = 0; j < 4; ++j) wpre += (j < w) ? wsum[j] : 0;
    if (tid == blockIdx.x) bpre = x + wpre - vv;   // exclusive prefix of this block
    __syncthreads();
    int gid = blockIdx.x * 256 + tid;
    if (gid < NN) offsets[gid] += bpre;
    if (gid == 0) offsets[NN] = EE;
}

// ---- scatter: atomic-free permute; ONE scattered 4B (tail) store/edge ----
__global__ void scatter(const int* __restrict__ eh, const int* __restrict__ et,
                        const int* __restrict__ rank, const int* __restrict__ offsets,
                        int* __restrict__ csr_tail) {
    int e4 = (blockIdx.x * 256 + threadIdx.x) * 4;
    if (e4 >= EE) return;
    int4 h = *(const int4*)(eh + e4);
    int4 t = *(const int4*)(et + e4);
    int4 r = *(const int4*)(rank + e4);
    int s0 = offsets[clampN(h.x)] + r.x;
    if ((unsigned)s0 < EE) csr_tail[s0] = clampN(t.x);
    int s1 = offsets[clampN(h.y)] + r.y;
    if ((unsigned)s1 < EE) csr_tail[s1] = clampN(t.y);
    int s2 = offsets[clampN(h.z)] + r.z;
    if ((unsigned)s2 < EE) csr_tail[s2] = clampN(t.z);
    int s3 = offsets[clampN(h.w)] + r.w;
    if ((unsigned)s3 < EE) csr_tail[s3] = clampN(t.w);
}

// ---- zat: fused Z-accum + per-edge dots/softmax + deg sums (8 nodes) ----
__global__ void zat(const int* __restrict__ offsets, const int* __restrict__ csr_tail,
                    const __half* __restrict__ Xh, const float* __restrict__ d0a,
                    const __half* __restrict__ Ttab,
                    __half* __restrict__ s4, float* __restrict__ dcol1) {
    __shared__ __half zn[8][72];        // 144B row stride (+16B pad: no bank confl)
    __shared__ float ssum[8][4];        // per-node per-intent score sums
    __shared__ int soff[9];
    int tid = threadIdx.x;
    int n0 = blockIdx.x * 8;            // 8 | NN, always full
    if (tid < 9) soff[tid] = offsets[n0 + tid];
    if (tid >= 32 && tid < 64) ssum[(tid - 32) >> 2][tid & 3] = 0.f;
    __syncthreads();

    // phase A: per 32-lane group, accumulate Z = sum d0[t]*Xh[t], norm -> LDS
    {
        int g = tid >> 5, cc = tid & 31;
        int s0 = soff[g], s1 = soff[g + 1];
        float accx = 0.f, accy = 0.f;
        for (int base = s0; base < s1; base += 4) {
            #pragma unroll
            for (int u = 0; u < 4; ++u) {
                int kk = base + u;
                bool act = kk < s1;
                int kc = act ? kk : s0;          // in-bounds; deg >= 1 always
                int t = act ? csr_tail[kc] : NN; // NN = zero row (Xh row = 0)
                float d0v = d0a[t];              // broadcast, L2-resident
                __half2 y = *(const __half2*)(Xh + (size_t)t * 64 + cc * 2);
                float2 yf = __half22float2(y);
                accx = fmaf(d0v, yf.x, accx);
                accy = fmaf(d0v, yf.y, accy);
            }
        }
        float ss = accx * accx + accy * accy;
        ss += __shfl_xor(ss, 1, 64);
        ss += __shfl_xor(ss, 2, 64);
        ss += __shfl_xor(ss, 4, 64);             // 8-lane group = 1 intent
        float inv = rsqrtf(fmaxf(ss, 1e-12f));
        *(__half2*)&zn[g][cc * 2] = __floats2half2_rn(accx * inv, accy * inv);
    }
    __syncthreads();

    // phase B: per-edge dots + softmax over the block's edge span
    int e0 = soff[0], e1 = soff[8];
    for (int k = e0 + tid; k < e1; k += 256) {
        int hl = 0;
        #pragma unroll
        for (int j = 1; j < 8; ++j) hl += (k >= soff[j]) ? 1 : 0;
        int t = csr_tail[k];
        const float4* tp = (const float4*)(Ttab + (size_t)t * 64);
        float dot[4];
        #pragma unroll
        for (int i = 0; i < 4; ++i) {
            float4 za = *(const float4*)&zn[hl][i * 16];
            float4 zb = *(const float4*)&zn[hl][i * 16 + 8];
            float4 ta = tp[2 * i], tb = tp[2 * i + 1];
            __half2 acc = __floats2half2_rn(0.f, 0.f);
            acc = __hfma2(bch2(za.x), bch2(ta.x), acc);
            acc = __hfma2(bch2(za.y), bch2(ta.y), acc);
            acc = __hfma2(bch2(za.z), bch2(ta.z), acc);
            acc = __hfma2(bch2(za.w), bch2(ta.w), acc);
            acc = __hfma2(bch2(zb.x), bch2(tb.x), acc);
            acc = __hfma2(bch2(zb.y), bch2(tb.y), acc);
            acc = __hfma2(bch2(zb.z), bch2(tb.z), acc);
            acc = __hfma2(bch2(zb.w), bch2(tb.w), acc);
            float2 f = __half22float2(acc);
            dot[i] = f.x + f.y;
        }
        float mx = fmaxf(fmaxf(dot[0], dot[1]), fmaxf(dot[2], dot[3]));
        float q0 = __expf(dot[0] - mx), q1 = __expf(dot[1] - mx);
        float q2 = __expf(dot[2] - mx), q3 = __expf(dot[3] - mx);
        float inv = 1.f / (q0 + q1 + q2 + q3);
        q0 *= inv; q1 *= inv; q2 *= inv; q3 *= inv;
        __half2 o01 = __floats2half2_rn(q0, q1);
        __half2 o23 = __floats2half2_rn(q2, q3);
        int2 st;
        st.x = __builtin_bit_cast(int, o01);
        st.y = __builtin_bit_cast(int, o23);
        *(int2*)(s4 + (size_t)k * 4) = st;
        atomicAdd(&ssum[hl][0], q0);
        atomicAdd(&ssum[hl][1], q1);
        atomicAdd(&ssum[hl][2], q2);
        atomicAdd(&ssum[hl][3], q3);
    }
    __syncthreads();

    // phase C: dcol1 from LDS sums
    if (tid < 32) {
        int nn = n0 + (tid >> 2);
        dcol1[nn * 4 + (tid & 3)] = rsqrtf(fmaxf(ssum[tid >> 2][tid & 3], 1e-30f));
    }
}

// ---- output pass: Z2 gather + finalize ----
// wave = 2 nodes x 32 half2-ch lanes. Per edge: broadcast csr_tail + s4 +
// dcol1[t] (L2-resident); 32 lanes gather one full 128B Xh row (shared,
// warm table); y1 = d1[t]*xh computed in fp32 in-register. float2 store.
__global__ void outk(const int* __restrict__ offsets, const int* __restrict__ csr_tail,
                     const __half* __restrict__ Xh, const __half* __restrict__ s4,
                     const float* __restrict__ dcol1,
                     const float* __restrict__ Gu, const float* __restrict__ Gi,
                     float* __restrict__ out) {
    int tid = threadIdx.x;
    int n = blockIdx.x * 8 + (tid >> 5);
    if (n >= NN) return;
    int cc = tid & 31;                           // half2-channel (2cc, 2cc+1)
    int i = cc >> 3;                             // intent of this lane's channels
    int s0 = offsets[n], s1 = offsets[n + 1];
    float accx = 0.f, accy = 0.f;
    for (int base = s0; base < s1; base += 4) {
        #pragma unroll
        for (int u = 0; u < 4; ++u) {
            int kk = base + u;
            bool act = kk < s1;
            int kc = act ? kk : s0;              // in-bounds; deg >= 1 always
            int t = csr_tail[kc];
            int2 raw = *(const int2*)(s4 + (size_t)kc * 4);
            int word = (cc & 16) ? raw.y : raw.x;
            unsigned short us = (unsigned short)(word >> ((cc & 8) ? 16 : 0));
            float s = act ? __half2float(__builtin_bit_cast(__half, us)) : 0.f;
            float w = s * dcol1[t * 4 + i];      // s * d1[tail][intent]
            __half2 y = *(const __half2*)(Xh + (size_t)t * 64 + cc * 2);
            float2 yf = __half22float2(y);
            accx = fmaf(w, yf.x, accx);
            accy = fmaf(w, yf.y, accy);
        }
    }
    float d = dcol1[n * 4 + i];
    int ch = cc * 2;
    const float* xr = (n < NUSERS) ? (Gu + (size_t)n * 64 + ch)
                                   : (Gi + (size_t)(n - NUSERS) * 64 + ch);
    float2 x2 = *(const float2*)xr;
    float2 o;
    o.x = 0.5f * (x2.x + d * accx);
    o.y = 0.5f * (x2.y + d * accy);
    *(float2*)(out + (size_t)n * 64 + ch) = o;
}

// ---- launch ----

extern "C" void kernel_launch(void* const* d_in, const int* in_sizes, int n_in,
                              void* d_out, int out_size, void* d_ws, size_t ws_size,
                              hipStream_t stream) {
    const float* Gu = (const float*)d_in[0];
    const float* Gi = (const float*)d_in[1];
    const int* eh = (const int*)d_in[2];
    const int* et = (const int*)d_in[3];
    float* out = (float*)d_out;

    char* p = (char*)d_ws;
    __half* s4       = (__half*)p;     p += (size_t)EE * 4 * 2;       // 6.4 MB
    int*    csr_tail = (int*)p;        p += (size_t)EE * 4;           // 3.2 MB
    int*    rank     = (int*)p;        p += (size_t)EE * 4;           // 3.2 MB
    int*    offsets  = (int*)p;        p += ((size_t)(NN + 1) * 4 + 15) / 16 * 16;
    int*    deg0     = (int*)p;        p += (size_t)NN * 4;
    int*    bsum     = (int*)p;        p += ((size_t)SCAN_B * 4 + 15) / 16 * 16;
    float*  dcol1    = (float*)p;      p += (size_t)NN * 4 * 4;       // 960 KB
    float*  d0a      = (float*)p;      p += ((size_t)(NN + 1) * 4 + 15) / 16 * 16;
    __half* Xh       = (__half*)p;     p += (size_t)(NN + 1) * 64 * 2; // 7.68 MB
    __half* Ttab     = (__half*)p;     // 7.68 MB -> total ~30 MB

    // CSR build: count (+rank) overlapped with table prep (tanh VALU work)
    hipMemsetAsync(deg0, 0, NN * sizeof(int), stream);
    count_prep<<<EV_B + NW1_B, 256, 0, stream>>>(eh, deg0, rank, Gu, Gi, Xh, Ttab);
    scan_local<<<SCAN_B, 256, 0, stream>>>(deg0, offsets, bsum, d0a);
    scan_add2<<<SCAN_B, 256, 0, stream>>>(offsets, bsum);

    // atomic-free edge permute (tail-only 4B scatter)
    scatter<<<EV_B, 256, 0, stream>>>(eh, et, rank, offsets, csr_tail);

    // fused iter-0: Z-accum (LDS, d0 in-register) + dots/softmax + deg sums
    zat<<<N8_B, 256, 0, stream>>>(offsets, csr_tail, Xh, d0a, Ttab, s4, dcol1);

    // iter 1 propagate + finalize: d1 in-register, shared warm Xh table
    outk<<<N8_B, 256, 0, stream>>>(offsets, csr_tail, Xh, s4, dcol1, Gu, Gi, out);
}